// Round 2
// baseline (28124.850 us; speedup 1.0000x reference)
//
#include <hip/hip_runtime.h>
#include <math.h>

// ---- problem dims ----
static constexpr int D_B = 8;
static constexpr int D_S = 8192;
static constexpr int D_H = 256;
static constexpr int D_L = 4;
static constexpr int TOK = D_B * D_S;          // 65536
static constexpr float NORMALIZER = 0.4204482076268573f;  // 32^-0.25
static constexpr float RATIO = 0.125f;                    // 64^-0.5
static constexpr float KEPS = 1e-4f;

// ---- workspace layout (floats) ----  total = 50,468,928 floats = 201,875,712 B
static constexpr size_t OFF_H    = 0;           // 16,777,216  residual stream
static constexpr size_t OFF_XN   = 16777216;    // 16,777,216  LN out / attn out
static constexpr size_t OFF_B1   = 33554432;    // 16,777,216  k -> q -> FFN mid (quarters)
static constexpr size_t OFF_KMAX = 50331648;    // 64 (uint32 keys)
static constexpr size_t OFF_KSUM = 50331712;    // 4,096
static constexpr size_t OFF_CTX  = 50335808;    // 131,072
static constexpr size_t OFF_POOL = 50466880;    // 2,048
static constexpr size_t TOTAL_F  = 50468928;
static constexpr size_t NEED_BYTES = TOTAL_F * 4;  // 201,875,712

// ================= ws-too-small telemetry =================
__global__ void report_kernel(float* out, float v) {
  if (threadIdx.x < 16) out[threadIdx.x] = v;
}

// ================= zero scratch =================
__global__ __launch_bounds__(256) void zero_kernel(float* p, int n) {
  int i = blockIdx.x * 256 + threadIdx.x;
  if (i < n) p[i] = 0.f;
}

// ================= embed: h = x @ emb_w + emb_b + pos =================
__global__ __launch_bounds__(256) void embed_kernel(
    const float* __restrict__ x, const float* __restrict__ ew,
    const float* __restrict__ eb, const float* __restrict__ pos,
    float* __restrict__ h) {
  __shared__ float xs[64];
  int t = blockIdx.x;
  int j = threadIdx.x;
  if (j < 64) xs[j] = x[t * 64 + j];
  __syncthreads();
  float acc = 0.f;
#pragma unroll 8
  for (int i = 0; i < 64; ++i) acc += xs[i] * ew[i * 256 + j];
  int s = t & (D_S - 1);
  h[(size_t)t * 256 + j] = acc + eb[j] + pos[(size_t)s * 256 + j];
}

// ================= layernorm: one wave per token =================
__global__ __launch_bounds__(256) void ln_kernel(
    const float* __restrict__ src, float* __restrict__ dst,
    const float* __restrict__ g, const float* __restrict__ b) {
  int wv = threadIdx.x >> 6, lane = threadIdx.x & 63;
  int t = blockIdx.x * 4 + wv;
  const float4 v = *(const float4*)(src + (size_t)t * 256 + lane * 4);
  float s1 = v.x + v.y + v.z + v.w;
  float s2 = v.x * v.x + v.y * v.y + v.z * v.z + v.w * v.w;
  for (int off = 32; off; off >>= 1) {
    s1 += __shfl_xor(s1, off);
    s2 += __shfl_xor(s2, off);
  }
  float mu = s1 * (1.f / 256.f);
  float var = s2 * (1.f / 256.f) - mu * mu;
  float rs = rsqrtf(var + 1e-5f);
  float4 gg = *(const float4*)(g + lane * 4);
  float4 bb = *(const float4*)(b + lane * 4);
  float4 o;
  o.x = (v.x - mu) * rs * gg.x + bb.x;
  o.y = (v.y - mu) * rs * gg.y + bb.y;
  o.z = (v.z - mu) * rs * gg.z + bb.z;
  o.w = (v.w - mu) * rs * gg.w + bb.w;
  *(float4*)(dst + (size_t)t * 256 + lane * 4) = o;
}

// ================= fp32 tiled GEMM: D = act(A@W + bias) [+ D] =================
template <int ACT, int ACC>
__global__ __launch_bounds__(256) void gemm_kernel(
    const float* __restrict__ A, const float* __restrict__ W,
    const float* __restrict__ bias, float* __restrict__ D,
    int N, int K) {
  __shared__ float As[16][68];
  __shared__ float Ws[16][68];
  int tid = threadIdx.x;
  int bm = blockIdx.x * 64, bn = blockIdx.y * 64;
  int ty = tid >> 4, tx = tid & 15;
  int m0 = ty * 4, n0 = tx * 4;
  int arow = tid >> 2, akk = (tid & 3) * 4;
  int wrow = tid >> 4, wcol = (tid & 15) * 4;
  const float* Ap = A + (size_t)(bm + arow) * K + akk;
  const float* Wp = W + (size_t)wrow * N + bn + wcol;
  float c[4][4] = {};
  for (int k0 = 0; k0 < K; k0 += 16) {
    float4 a4 = *(const float4*)(Ap + k0);
    float4 w4 = *(const float4*)(Wp + (size_t)k0 * N);
    __syncthreads();
    As[akk + 0][arow] = a4.x;
    As[akk + 1][arow] = a4.y;
    As[akk + 2][arow] = a4.z;
    As[akk + 3][arow] = a4.w;
    *(float4*)&Ws[wrow][wcol] = w4;
    __syncthreads();
#pragma unroll
    for (int k = 0; k < 16; ++k) {
      float4 av = *(const float4*)&As[k][m0];
      float4 wv = *(const float4*)&Ws[k][n0];
      c[0][0] += av.x * wv.x; c[0][1] += av.x * wv.y; c[0][2] += av.x * wv.z; c[0][3] += av.x * wv.w;
      c[1][0] += av.y * wv.x; c[1][1] += av.y * wv.y; c[1][2] += av.y * wv.z; c[1][3] += av.y * wv.w;
      c[2][0] += av.z * wv.x; c[2][1] += av.z * wv.y; c[2][2] += av.z * wv.z; c[2][3] += av.z * wv.w;
      c[3][0] += av.w * wv.x; c[3][1] += av.w * wv.y; c[3][2] += av.w * wv.z; c[3][3] += av.w * wv.w;
    }
  }
  float bvals[4];
#pragma unroll
  for (int j = 0; j < 4; ++j) bvals[j] = bias ? bias[bn + n0 + j] : 0.f;
#pragma unroll
  for (int i = 0; i < 4; ++i) {
    float* dp = D + (size_t)(bm + m0 + i) * N + bn + n0;
#pragma unroll
    for (int j = 0; j < 4; ++j) {
      float val = c[i][j] + bvals[j];
      if (ACT == 1) val = 0.5f * val * (1.f + erff(val * 0.70710678118654752f));
      if (ACC == 1) val += dp[j];
      dp[j] = val;
    }
  }
}

// ================= k row-max pass: one wave per (bh, n); atomicMax into kmax =================
__global__ __launch_bounds__(256) void rowmax_kernel(
    const float* __restrict__ kbuf, const float* __restrict__ proj,
    unsigned int* __restrict__ kmaxk) {
  __shared__ float pT[32 * 65];
  __shared__ float sq[4][32];
  int tid = threadIdx.x;
#pragma unroll
  for (int u = 0; u < 8; ++u) {
    int i = tid + u * 256;
    pT[(i & 31) * 65 + (i >> 5)] = proj[i];
  }
  if (tid < 128) {
    int w = tid >> 5, d = tid & 31;
    int task = blockIdx.x * 4 + w;
    int bh = task >> 13, n = task & (D_S - 1);
    int b = bh >> 3, hd = bh & 7;
    sq[w][d] = kbuf[((size_t)(b * D_S + n)) * 256 + hd * 32 + d] * NORMALIZER;
  }
  __syncthreads();
  int wv = tid >> 6, lane = tid & 63;
  int task = blockIdx.x * 4 + wv;
  int bh = task >> 13;
  float xp = 0.f;
#pragma unroll
  for (int d = 0; d < 32; ++d) xp += sq[wv][d] * pT[d * 65 + lane];
  for (int off = 32; off; off >>= 1) xp = fmaxf(xp, __shfl_xor(xp, off));
  if (lane == 0) {
    unsigned int u = __float_as_uint(xp);
    unsigned int key = (u & 0x80000000u) ? ~u : (u | 0x80000000u);
    atomicMax(kmaxk + bh, key);
  }
}

// ====== context: recompute kp (from k) and v (from xn@wv) in LDS; accumulate ctx/ksum ======
// grid (64 bh, 16 chunks of 512 tokens); block 256; sub-chunks of 32 tokens.
__global__ __launch_bounds__(256) void context_kernel(
    const float* __restrict__ kbuf, const float* __restrict__ xn,
    const float* __restrict__ wv, const float* __restrict__ proj,
    const unsigned int* __restrict__ kmaxk,
    float* __restrict__ ksum, float* __restrict__ ctx) {
  __shared__ float pT[32 * 65];        // proj^T [d][m]
  __shared__ float wvS[256 * 32];      // wv head block [c][e]
  __shared__ float xnT[32][33];        // xn c-tile
  __shared__ float kS[32][33];         // scaled k rows
  __shared__ float vS[32][33];         // recomputed v rows
  __shared__ float kpS[32 * 65];       // kp values
  __shared__ float dgS[32];
  int tid = threadIdx.x;
  int bh = blockIdx.x, ch = blockIdx.y;
  int b = bh >> 3, hd = bh & 7;
#pragma unroll
  for (int u = 0; u < 8; ++u) {
    int i = tid + u * 256;
    pT[(i & 31) * 65 + (i >> 5)] = proj[i];
  }
#pragma unroll
  for (int u = 0; u < 32; ++u) {
    int i = tid + u * 256;             // 8192 elements
    int c = i >> 5, e = i & 31;
    wvS[c * 32 + e] = wv[(size_t)c * 256 + hd * 32 + e];
  }
  unsigned int mk = kmaxk[bh];
  float mx = __uint_as_float((mk & 0x80000000u) ? (mk & 0x7fffffffu) : ~mk);
  int m = tid & 63, eg = tid >> 6;
  float acc[8] = {};
  float ks = 0.f;
  for (int sub = 0; sub < 16; ++sub) {
    int n0 = ch * 512 + sub * 32;
    // A: stage scaled k rows (32x32)
    {
      int row = tid >> 3, d0 = (tid & 7) * 4;
      float4 k4 = *(const float4*)(kbuf + ((size_t)(b * D_S + n0 + row)) * 256 + hd * 32 + d0);
      kS[row][d0 + 0] = k4.x * NORMALIZER;
      kS[row][d0 + 1] = k4.y * NORMALIZER;
      kS[row][d0 + 2] = k4.z * NORMALIZER;
      kS[row][d0 + 3] = k4.w * NORMALIZER;
    }
    // B/C: v = xn_rows @ wv_head, tiled over c in 8 chunks of 32
    float vacc[4] = {};
    for (int cc = 0; cc < 8; ++cc) {
      __syncthreads();
      {
        int row = tid >> 3, c0 = (tid & 7) * 4;
        *(float4*)&xnT[row][c0] =
            *(const float4*)(xn + ((size_t)(b * D_S + n0 + row)) * 256 + cc * 32 + c0);
      }
      __syncthreads();
#pragma unroll
      for (int r = 0; r < 4; ++r) {
        int idx = tid + r * 256;
        int n = idx >> 5, e = idx & 31;
        float s = 0.f;
#pragma unroll
        for (int j = 0; j < 32; ++j) s += xnT[n][j] * wvS[(cc * 32 + j) * 32 + e];
        vacc[r] += s;
      }
    }
    // D: commit v rows
#pragma unroll
    for (int r = 0; r < 4; ++r) {
      int idx = tid + r * 256;
      vS[idx >> 5][idx & 31] = vacc[r];
    }
    // E: diag
    if (tid < 32) {
      float s = 0.f;
#pragma unroll
      for (int d = 0; d < 32; ++d) { float xv = kS[tid][d]; s += xv * xv; }
      dgS[tid] = 0.5f * s;
    }
    __syncthreads();
    // F: kp = RATIO*(exp(k.proj - diag - mx)+eps)
#pragma unroll
    for (int i = 0; i < 8; ++i) {
      int n = eg * 8 + i;
      float xp = 0.f;
#pragma unroll
      for (int d = 0; d < 32; ++d) xp += kS[n][d] * pT[d * 65 + m];
      kpS[n * 65 + m] = RATIO * (__expf(xp - dgS[n] - mx) + KEPS);
    }
    __syncthreads();
    // G: accumulate ctx[m][e] and ksum[m]
#pragma unroll
    for (int n = 0; n < 32; ++n) {
      float kv = kpS[n * 65 + m];
      ks += kv;
#pragma unroll
      for (int j = 0; j < 8; ++j) acc[j] += kv * vS[n][eg * 8 + j];
    }
    __syncthreads();
  }
  float* cp = ctx + (size_t)(bh * 64 + m) * 32 + eg * 8;
#pragma unroll
  for (int j = 0; j < 8; ++j) atomicAdd(cp + j, acc[j]);
  if (eg == 0) atomicAdd(ksum + bh * 64 + m, ks);
}

// ====== attention out: recompute qp from q in LDS; out = (qp@ctx)/(qp@ksum) ======
// grid (64 bh, 128 chunks of 64 tokens); block 256.
__global__ __launch_bounds__(256) void attn_kernel(
    const float* __restrict__ q, const float* __restrict__ proj,
    const float* __restrict__ ctx, const float* __restrict__ ksum,
    float* __restrict__ out) {
  __shared__ float pT[32 * 65];
  __shared__ float qS[64][33];
  __shared__ float xpS[64 * 65];
  __shared__ float cS[64 * 32];
  __shared__ float ksS[64];
  __shared__ float dgS[64];
  __shared__ float mxS[64];
  int tid = threadIdx.x;
  int bh = blockIdx.x, ch = blockIdx.y;
  int b = bh >> 3, hd = bh & 7;
  int n0 = ch * 64;
#pragma unroll
  for (int u = 0; u < 8; ++u) {
    int i = tid + u * 256;
    pT[(i & 31) * 65 + (i >> 5)] = proj[i];
  }
#pragma unroll
  for (int u = 0; u < 8; ++u) {
    int i = tid + u * 256;
    cS[i] = ctx[bh * 2048 + i];          // cS[m*32+e]
  }
  if (tid < 64) ksS[tid] = ksum[bh * 64 + tid];
  {
    int row = tid >> 2, d0 = (tid & 3) * 8;
    const float* src = q + ((size_t)(b * D_S + n0 + row)) * 256 + hd * 32 + d0;
    float4 a = ((const float4*)src)[0];
    float4 c4 = ((const float4*)src)[1];
    qS[row][d0 + 0] = a.x * NORMALIZER;  qS[row][d0 + 1] = a.y * NORMALIZER;
    qS[row][d0 + 2] = a.z * NORMALIZER;  qS[row][d0 + 3] = a.w * NORMALIZER;
    qS[row][d0 + 4] = c4.x * NORMALIZER; qS[row][d0 + 5] = c4.y * NORMALIZER;
    qS[row][d0 + 6] = c4.z * NORMALIZER; qS[row][d0 + 7] = c4.w * NORMALIZER;
  }
  __syncthreads();
  int m = tid & 63, eg = tid >> 6;
#pragma unroll
  for (int i = 0; i < 16; ++i) {
    int n = eg * 16 + i;
    float xp = 0.f;
#pragma unroll
    for (int d = 0; d < 32; ++d) xp += qS[n][d] * pT[d * 65 + m];
    xpS[n * 65 + m] = xp;
  }
  if (tid < 64) {
    float s = 0.f;
#pragma unroll
    for (int d = 0; d < 32; ++d) { float xv = qS[tid][d]; s += xv * xv; }
    dgS[tid] = 0.5f * s;
  }
  __syncthreads();
  if (tid < 64) {
    float mxv = -3.4e38f;
#pragma unroll
    for (int j = 0; j < 64; ++j) mxv = fmaxf(mxv, xpS[tid * 65 + j]);
    mxS[tid] = mxv;
  }
  __syncthreads();
#pragma unroll
  for (int i = 0; i < 16; ++i) {
    int n = eg * 16 + i;
    xpS[n * 65 + m] = RATIO * (__expf(xpS[n * 65 + m] - dgS[n] - mxS[n]) + KEPS);
  }
  __syncthreads();
  {
    int e = tid & 31, ng = tid >> 5;
#pragma unroll
    for (int i = 0; i < 8; ++i) {
      int n = ng * 8 + i;
      float num = 0.f, den = 0.f;
#pragma unroll
      for (int mm = 0; mm < 64; ++mm) {
        float qv = xpS[n * 65 + mm];
        num += qv * cS[mm * 32 + e];
        den += qv * ksS[mm];
      }
      out[((size_t)(b * D_S + n0 + n)) * 256 + hd * 32 + e] = num / den;
    }
  }
}

// ================= mean pool (partial sums via atomics) =================
__global__ __launch_bounds__(256) void pool_kernel(
    const float* __restrict__ h, float* __restrict__ pooled) {
  int b = blockIdx.x, chunk = blockIdx.y, j = threadIdx.x;
  const float* hp = h + (size_t)(b * D_S + chunk * 256) * 256 + j;
  float acc = 0.f;
#pragma unroll 4
  for (int s = 0; s < 256; ++s) acc += hp[(size_t)s * 256];
  atomicAdd(pooled + b * 256 + j, acc);
}

// ================= final FC =================
__global__ __launch_bounds__(64) void final_kernel(
    const float* __restrict__ pooled, const float* __restrict__ fcw,
    const float* __restrict__ fcb, float* __restrict__ out) {
  int tid = threadIdx.x;
  if (tid >= 16) return;
  int b = tid >> 1, c = tid & 1;
  float acc = 0.f;
  for (int j = 0; j < 256; ++j) acc += pooled[b * 256 + j] * fcw[j * 2 + c];
  out[b * 2 + c] = acc * (1.f / 8192.f) + fcb[c];
}

extern "C" void kernel_launch(void* const* d_in, const int* in_sizes, int n_in,
                              void* d_out, int out_size, void* d_ws, size_t ws_size,
                              hipStream_t stream) {
  const float* x     = (const float*)d_in[0];
  const float* emb_w = (const float*)d_in[1];
  const float* emb_b = (const float*)d_in[2];
  const float* pos   = (const float*)d_in[3];
  const float* ln1_g = (const float*)d_in[4];
  const float* ln1_b = (const float*)d_in[5];
  const float* wq    = (const float*)d_in[6];
  const float* wk    = (const float*)d_in[7];
  const float* wv    = (const float*)d_in[8];
  const float* wo    = (const float*)d_in[9];
  const float* bo    = (const float*)d_in[10];
  const float* ln2_g = (const float*)d_in[11];
  const float* ln2_b = (const float*)d_in[12];
  const float* w1    = (const float*)d_in[13];
  const float* b1    = (const float*)d_in[14];
  const float* w2    = (const float*)d_in[15];
  const float* b2    = (const float*)d_in[16];
  const float* proj  = (const float*)d_in[17];
  const float* fc_w  = (const float*)d_in[18];
  const float* fc_b  = (const float*)d_in[19];

  if (ws_size < NEED_BYTES) {
    // telemetry: report the actual ws_size via the absmax check
    report_kernel<<<1, 64, 0, stream>>>((float*)d_out, (float)ws_size);
    return;
  }

  float* ws = (float*)d_ws;
  float* h      = ws + OFF_H;
  float* xn     = ws + OFF_XN;
  float* buf1   = ws + OFF_B1;
  unsigned int* kmaxk = (unsigned int*)(ws + OFF_KMAX);
  float* ksum   = ws + OFF_KSUM;
  float* ctx    = ws + OFF_CTX;
  float* pooled = ws + OFF_POOL;

  embed_kernel<<<TOK, 256, 0, stream>>>(x, emb_w, emb_b, pos, h);

  for (int l = 0; l < D_L; ++l) {
    const float* pj = proj + l * 2048;
    ln_kernel<<<TOK / 4, 256, 0, stream>>>(h, xn, ln1_g + l * 256, ln1_b + l * 256);
    // k into buf1
    gemm_kernel<0, 0><<<dim3(TOK / 64, 4), 256, 0, stream>>>(xn, wk + l * 65536, nullptr, buf1, 256, 256);
    // zero kmax + ksum + ctx (contiguous region)
    zero_kernel<<<(64 + 4096 + 131072 + 255) / 256, 256, 0, stream>>>(ws + OFF_KMAX, 64 + 4096 + 131072);
    rowmax_kernel<<<TOK * 8 / 4, 256, 0, stream>>>(buf1, pj, kmaxk);
    context_kernel<<<dim3(64, 16), 256, 0, stream>>>(buf1, xn, wv + l * 65536, pj, kmaxk, ksum, ctx);
    // q into buf1 (k is dead now)
    gemm_kernel<0, 0><<<dim3(TOK / 64, 4), 256, 0, stream>>>(xn, wq + l * 65536, nullptr, buf1, 256, 256);
    // attention output overwrites xn
    attn_kernel<<<dim3(64, 128), 256, 0, stream>>>(buf1, pj, ctx, ksum, xn);
    gemm_kernel<0, 1><<<dim3(TOK / 64, 4), 256, 0, stream>>>(xn, wo + l * 65536, bo + l * 256, h, 256, 256);

    ln_kernel<<<TOK / 4, 256, 0, stream>>>(h, xn, ln2_g + l * 256, ln2_b + l * 256);
    // FFN in 4 token-quarters, mid lives in buf1 (16384x1024 floats exactly)
    for (int qtr = 0; qtr < 4; ++qtr) {
      const float* aA = xn + (size_t)qtr * 16384 * 256;
      float* hD = h + (size_t)qtr * 16384 * 256;
      gemm_kernel<1, 0><<<dim3(256, 16), 256, 0, stream>>>(aA, w1 + l * 262144, b1 + l * 1024, buf1, 1024, 256);
      gemm_kernel<0, 1><<<dim3(256, 4), 256, 0, stream>>>(buf1, w2 + l * 262144, b2 + l * 256, hD, 256, 1024);
    }
  }

  zero_kernel<<<8, 256, 0, stream>>>(pooled, 2048);
  pool_kernel<<<dim3(8, 32), 256, 0, stream>>>(h, pooled);
  final_kernel<<<1, 64, 0, stream>>>(pooled, fc_w, fc_b, (float*)d_out);
}

// Round 3
// 12839.549 us; speedup vs baseline: 2.1905x; 2.1905x over previous
//
#include <hip/hip_runtime.h>
#include <math.h>

// ---- problem dims ----
static constexpr int D_B = 8;
static constexpr int D_S = 8192;
static constexpr int D_L = 4;
static constexpr int TOK = D_B * D_S;          // 65536
static constexpr float NORMALIZER = 0.4204482076268573f;  // 32^-0.25
static constexpr float RATIO = 0.125f;                    // 64^-0.5
static constexpr float KEPS = 1e-4f;
static constexpr int QTOK = 16384;             // tokens per quarter (2 full b)

// ---- workspace layout (floats) ----
static constexpr size_t OFF_H    = 0;           // 16,777,216  residual
static constexpr size_t OFF_XN   = 16777216;    // 16,777,216  LN out
static constexpr size_t OFF_B1   = 33554432;    // 16,777,216  kp/v | qp/ao | FFN mid
// attention scratch packed in buf1 tail (beyond kp(8.4M)+v(4.2M)=12,582,912)
static constexpr size_t OFF_SCR   = OFF_B1 + 12582912;
static constexpr size_t OFF_WKP   = OFF_SCR + 0;        // 131,072
static constexpr size_t OFF_WQP   = OFF_SCR + 131072;   // 131,072
static constexpr size_t OFF_DIAGK = OFF_SCR + 262144;   // 524,288
static constexpr size_t OFF_DIAGQ = OFF_SCR + 786432;   // 524,288
static constexpr size_t OFF_KMAX  = OFF_SCR + 1310720;  // 64
static constexpr size_t OFF_PART  = OFF_SCR + 1310784;  // 1,048,576
static constexpr size_t OFF_PARTK = OFF_SCR + 2359360;  // 32,768
static constexpr size_t OFF_CTX   = OFF_SCR + 2392128;  // 131,072
static constexpr size_t OFF_KSUM  = OFF_SCR + 2523200;  // 4,096
static constexpr size_t OFF_POOL  = OFF_SCR + 2527296;  // 2,048
static constexpr size_t NEED_BYTES = 201875712;  // proven OK in round 2

__global__ void report_kernel(float* out, float v) {
  if (threadIdx.x < 16) out[threadIdx.x] = v;
}

__global__ __launch_bounds__(256) void zero_kernel(float* p, int n) {
  int i = blockIdx.x * 256 + threadIdx.x;
  if (i < n) p[i] = 0.f;
}

// ================= embed =================
__global__ __launch_bounds__(256) void embed_kernel(
    const float* __restrict__ x, const float* __restrict__ ew,
    const float* __restrict__ eb, const float* __restrict__ pos,
    float* __restrict__ h) {
  __shared__ float xs[64];
  int t = blockIdx.x;
  int j = threadIdx.x;
  if (j < 64) xs[j] = x[t * 64 + j];
  __syncthreads();
  float acc = 0.f;
#pragma unroll 8
  for (int i = 0; i < 64; ++i) acc += xs[i] * ew[i * 256 + j];
  int s = t & (D_S - 1);
  h[(size_t)t * 256 + j] = acc + eb[j] + pos[(size_t)s * 256 + j];
}

// ================= layernorm =================
__global__ __launch_bounds__(256) void ln_kernel(
    const float* __restrict__ src, float* __restrict__ dst,
    const float* __restrict__ g, const float* __restrict__ b) {
  int wv = threadIdx.x >> 6, lane = threadIdx.x & 63;
  int t = blockIdx.x * 4 + wv;
  const float4 v = *(const float4*)(src + (size_t)t * 256 + lane * 4);
  float s1 = v.x + v.y + v.z + v.w;
  float s2 = v.x * v.x + v.y * v.y + v.z * v.z + v.w * v.w;
  for (int off = 32; off; off >>= 1) {
    s1 += __shfl_xor(s1, off);
    s2 += __shfl_xor(s2, off);
  }
  float mu = s1 * (1.f / 256.f);
  float var = s2 * (1.f / 256.f) - mu * mu;
  float rs = rsqrtf(var + 1e-5f);
  float4 gg = *(const float4*)(g + lane * 4);
  float4 bb = *(const float4*)(b + lane * 4);
  float4 o;
  o.x = (v.x - mu) * rs * gg.x + bb.x;
  o.y = (v.y - mu) * rs * gg.y + bb.y;
  o.z = (v.z - mu) * rs * gg.z + bb.z;
  o.w = (v.w - mu) * rs * gg.w + bb.w;
  *(float4*)(dst + (size_t)t * 256 + lane * 4) = o;
}

// ============ GEMM body macro: 64x64 tile, 4x4/thread, K multiple of 16 ============
#define GEMM64_BODY(A_, W_, K_)                                                  \
  __shared__ float As[16][68];                                                   \
  __shared__ float Ws[16][68];                                                   \
  int tid = threadIdx.x;                                                         \
  int bm = blockIdx.x * 64, bn = blockIdx.y * 64;                                \
  int ty = tid >> 4, tx = tid & 15;                                              \
  int m0 = ty * 4, n0 = tx * 4;                                                  \
  int arow = tid >> 2, akk = (tid & 3) * 4;                                      \
  int wrow = tid >> 4, wcol = (tid & 15) * 4;                                    \
  const float* Ap = (A_) + (size_t)(bm + arow) * (K_) + akk;                     \
  const float* Wp = (W_) + (size_t)wrow * N + bn + wcol;                         \
  float c[4][4] = {};                                                            \
  for (int k0 = 0; k0 < (K_); k0 += 16) {                                        \
    float4 a4 = *(const float4*)(Ap + k0);                                       \
    float4 w4 = *(const float4*)(Wp + (size_t)k0 * N);                           \
    __syncthreads();                                                             \
    As[akk + 0][arow] = a4.x;                                                    \
    As[akk + 1][arow] = a4.y;                                                    \
    As[akk + 2][arow] = a4.z;                                                    \
    As[akk + 3][arow] = a4.w;                                                    \
    *(float4*)&Ws[wrow][wcol] = w4;                                              \
    __syncthreads();                                                             \
    _Pragma("unroll") for (int k = 0; k < 16; ++k) {                             \
      float4 av = *(const float4*)&As[k][m0];                                    \
      float4 wv = *(const float4*)&Ws[k][n0];                                    \
      c[0][0] += av.x * wv.x; c[0][1] += av.x * wv.y; c[0][2] += av.x * wv.z; c[0][3] += av.x * wv.w; \
      c[1][0] += av.y * wv.x; c[1][1] += av.y * wv.y; c[1][2] += av.y * wv.z; c[1][3] += av.y * wv.w; \
      c[2][0] += av.z * wv.x; c[2][1] += av.z * wv.y; c[2][2] += av.z * wv.z; c[2][3] += av.z * wv.w; \
      c[3][0] += av.w * wv.x; c[3][1] += av.w * wv.y; c[3][2] += av.w * wv.z; c[3][3] += av.w * wv.w; \
    }                                                                            \
  }

// ================= plain GEMM: D = act(A@W + bias) [+ D] =================
template <int ACT, int ACC>
__global__ __launch_bounds__(256) void gemm_kernel(
    const float* __restrict__ A, const float* __restrict__ W,
    const float* __restrict__ bias, float* __restrict__ D,
    int N, int K) {
  GEMM64_BODY(A, W, K)
  float bvals[4];
#pragma unroll
  for (int j = 0; j < 4; ++j) bvals[j] = bias ? bias[bn + n0 + j] : 0.f;
#pragma unroll
  for (int i = 0; i < 4; ++i) {
    float* dp = D + (size_t)(bm + m0 + i) * N + bn + n0;
#pragma unroll
    for (int j = 0; j < 4; ++j) {
      float val = c[i][j] + bvals[j];
      if (ACT == 1) val = 0.5f * val * (1.f + erff(val * 0.70710678118654752f));
      if (ACC == 1) val += dp[j];
      dp[j] = val;
    }
  }
}

// ================= 128x128 GEMM for FFN =================
template <int ACT, int ACC>
__global__ __launch_bounds__(256) void gemm128_kernel(
    const float* __restrict__ A, const float* __restrict__ W,
    const float* __restrict__ bias, float* __restrict__ D,
    int N, int K) {
  __shared__ float As[16][136];
  __shared__ float Ws[16][136];
  int tid = threadIdx.x;
  int bm = blockIdx.x * 128, bn = blockIdx.y * 128;
  int arow = tid >> 1, ak = (tid & 1) * 8;
  int wrow = tid >> 4, wc = (tid & 15) * 8;
  const float* Ap = A + (size_t)(bm + arow) * K + ak;
  const float* Wp = W + (size_t)wrow * N + bn + wc;
  int ty = tid >> 4, tx = tid & 15;
  int m0 = ty * 8, n0 = tx * 8;
  float c[8][8] = {};
  for (int k0 = 0; k0 < K; k0 += 16) {
    float4 a0 = *(const float4*)(Ap + k0);
    float4 a1 = *(const float4*)(Ap + k0 + 4);
    float4 w0 = *(const float4*)(Wp + (size_t)k0 * N);
    float4 w1 = *(const float4*)(Wp + (size_t)k0 * N + 4);
    __syncthreads();
    As[ak + 0][arow] = a0.x; As[ak + 1][arow] = a0.y;
    As[ak + 2][arow] = a0.z; As[ak + 3][arow] = a0.w;
    As[ak + 4][arow] = a1.x; As[ak + 5][arow] = a1.y;
    As[ak + 6][arow] = a1.z; As[ak + 7][arow] = a1.w;
    *(float4*)&Ws[wrow][wc] = w0;
    *(float4*)&Ws[wrow][wc + 4] = w1;
    __syncthreads();
#pragma unroll
    for (int k = 0; k < 16; ++k) {
      float a[8], b[8];
      *(float4*)(a + 0) = *(const float4*)&As[k][m0];
      *(float4*)(a + 4) = *(const float4*)&As[k][m0 + 4];
      *(float4*)(b + 0) = *(const float4*)&Ws[k][n0];
      *(float4*)(b + 4) = *(const float4*)&Ws[k][n0 + 4];
#pragma unroll
      for (int i = 0; i < 8; ++i)
#pragma unroll
        for (int j = 0; j < 8; ++j) c[i][j] += a[i] * b[j];
    }
  }
  float bvals[8];
#pragma unroll
  for (int j = 0; j < 8; ++j) bvals[j] = bias ? bias[bn + n0 + j] : 0.f;
#pragma unroll
  for (int i = 0; i < 8; ++i) {
    float* dp = D + (size_t)(bm + m0 + i) * N + bn + n0;
#pragma unroll
    for (int j = 0; j < 8; ++j) {
      float val = c[i][j] + bvals[j];
      if (ACT == 1) val = 0.5f * val * (1.f + erff(val * 0.70710678118654752f));
      if (ACC == 1) val += dp[j];
      dp[j] = val;
    }
  }
}

// ================= WKP/WQP: out[c][h*64+m] = norm * sum_d w[c][h*32+d]*proj[m][d] =================
__global__ __launch_bounds__(256) void wproj_kernel(
    const float* __restrict__ w, const float* __restrict__ proj,
    float* __restrict__ out) {
  int idx = blockIdx.x * 256 + threadIdx.x;   // 131072
  int cc = idx >> 9, hm = idx & 511;
  int hd = hm >> 6, m = hm & 63;
  float s = 0.f;
#pragma unroll
  for (int d = 0; d < 32; ++d) s += w[cc * 256 + hd * 32 + d] * proj[m * 32 + d];
  out[cc * 512 + hm] = NORMALIZER * s;
}

// ================= passA: xp = xn@WKP, tile-max -> atomicMax per (b,head) =================
__global__ __launch_bounds__(256) void gemm_max_kernel(
    const float* __restrict__ A, const float* __restrict__ W,
    unsigned int* __restrict__ kmaxk) {
  const int N = 512;
  GEMM64_BODY(A, W, 256)
  float mx = c[0][0];
#pragma unroll
  for (int i = 0; i < 4; ++i)
#pragma unroll
    for (int j = 0; j < 4; ++j) mx = fmaxf(mx, c[i][j]);
  __shared__ float mred[256];
  mred[tid] = mx;
  __syncthreads();
  for (int s = 128; s; s >>= 1) {
    if (tid < s) mred[tid] = fmaxf(mred[tid], mred[tid + s]);
    __syncthreads();
  }
  if (tid == 0) {
    int b = bm >> 13;
    unsigned int u = __float_as_uint(mred[0]);
    unsigned int key = (u & 0x80000000u) ? ~u : (u | 0x80000000u);
    atomicMax(kmaxk + b * 8 + blockIdx.y, key);
  }
}

// ================= diag: k = xn@w, diag[t][head] = 0.5*norm^2*sum_d k^2 =================
__global__ __launch_bounds__(256) void gemm_diag_kernel(
    const float* __restrict__ A, const float* __restrict__ W,
    float* __restrict__ diag) {
  const int N = 256;
  GEMM64_BODY(A, W, 256)
  __shared__ float red[64][17];
#pragma unroll
  for (int i = 0; i < 4; ++i) {
    float s = c[i][0] * c[i][0] + c[i][1] * c[i][1] + c[i][2] * c[i][2] + c[i][3] * c[i][3];
    red[m0 + i][tx] = s;
  }
  __syncthreads();
  if (tid < 128) {
    int row = tid >> 1, hl = tid & 1;
    float s = 0.f;
#pragma unroll
    for (int t = 0; t < 8; ++t) s += red[row][hl * 8 + t];
    diag[(size_t)(bm + row) * 8 + blockIdx.y * 2 + hl] =
        0.5f * NORMALIZER * NORMALIZER * s;
  }
}

// ================= kp GEMM: out = ratio*(exp(xp - diag - mx) + eps) =================
__global__ __launch_bounds__(256) void gemm_kp_kernel(
    const float* __restrict__ A, const float* __restrict__ W,
    const float* __restrict__ diagk, const unsigned int* __restrict__ kmaxk,
    float* __restrict__ D, int tok0) {
  const int N = 512;
  GEMM64_BODY(A, W, 256)
  int head = blockIdx.y;
  int b = (tok0 + bm) >> 13;
  unsigned int mk = kmaxk[b * 8 + head];
  float mx = __uint_as_float((mk & 0x80000000u) ? (mk & 0x7fffffffu) : ~mk);
#pragma unroll
  for (int i = 0; i < 4; ++i) {
    int row = bm + m0 + i;
    float dg = diagk[(size_t)(tok0 + row) * 8 + head];
    float* dp = D + (size_t)row * 512 + bn + n0;
#pragma unroll
    for (int j = 0; j < 4; ++j)
      dp[j] = RATIO * (__expf(c[i][j] - dg - mx) + KEPS);
  }
}

// ================= qp GEMM: row-max over the head's 64 cols, then exp =================
__global__ __launch_bounds__(256) void gemm_qp_kernel(
    const float* __restrict__ A, const float* __restrict__ W,
    const float* __restrict__ diagq, float* __restrict__ D, int tok0) {
  const int N = 512;
  GEMM64_BODY(A, W, 256)
  int head = blockIdx.y;
  __shared__ float red[64][17];
#pragma unroll
  for (int i = 0; i < 4; ++i)
    red[m0 + i][tx] = fmaxf(fmaxf(c[i][0], c[i][1]), fmaxf(c[i][2], c[i][3]));
  __syncthreads();
#pragma unroll
  for (int i = 0; i < 4; ++i) {
    int row = m0 + i;
    float mx = red[row][0];
#pragma unroll
    for (int t = 1; t < 16; ++t) mx = fmaxf(mx, red[row][t]);
    float dg = diagq[(size_t)(tok0 + bm + row) * 8 + head];
    float* dp = D + (size_t)(bm + row) * 512 + bn + n0;
#pragma unroll
    for (int j = 0; j < 4; ++j)
      dp[j] = RATIO * (__expf(c[i][j] - dg - mx) + KEPS);
  }
}

// ===== ctxaccum: per (bh-local, s-chunk of 1024): part[m][e] = sum_n kp*v; partks[m] = sum kp =====
__global__ __launch_bounds__(256) void ctxaccum_kernel(
    const float* __restrict__ kp, const float* __restrict__ v,
    float* __restrict__ part, float* __restrict__ partks, int qtr) {
  __shared__ float kpS[64 * 64];
  __shared__ float vS[64 * 32];
  int tid = threadIdx.x;
  int bhl = blockIdx.x, chunk = blockIdx.y;
  int bloc = bhl >> 3, head = bhl & 7;
  int b = 2 * qtr + bloc;
  int bhg = b * 8 + head;
  int tl0 = bloc * 8192 + chunk * 1024;
  int m = tid & 63, eg = tid >> 6;
  float acc[8] = {};
  float ks = 0.f;
  for (int tile = 0; tile < 16; ++tile) {
    int nb = tl0 + tile * 64;
    __syncthreads();
#pragma unroll
    for (int i = 0; i < 16; ++i) {
      int idx = tid + i * 256;
      kpS[idx] = kp[(size_t)(nb + (idx >> 6)) * 512 + head * 64 + (idx & 63)];
    }
#pragma unroll
    for (int i = 0; i < 8; ++i) {
      int idx = tid + i * 256;
      vS[idx] = v[(size_t)(nb + (idx >> 5)) * 256 + head * 32 + (idx & 31)];
    }
    __syncthreads();
#pragma unroll 4
    for (int n = 0; n < 64; ++n) {
      float kv = kpS[n * 64 + m];
      if (eg == 0) ks += kv;
      const float* vr = &vS[n * 32 + eg * 8];
#pragma unroll
      for (int j = 0; j < 8; ++j) acc[j] += kv * vr[j];
    }
  }
  float* pp = part + (((size_t)bhg * 8 + chunk) * 64 + m) * 32 + eg * 8;
#pragma unroll
  for (int j = 0; j < 8; ++j) pp[j] = acc[j];
  if (eg == 0) partks[((size_t)bhg * 8 + chunk) * 64 + m] = ks;
}

// ================= ctxreduce =================
__global__ __launch_bounds__(256) void ctxreduce_kernel(
    const float* __restrict__ part, const float* __restrict__ partks,
    float* __restrict__ ctx, float* __restrict__ ksum) {
  int bh = blockIdx.x, tid = threadIdx.x;
#pragma unroll
  for (int i = 0; i < 8; ++i) {
    int idx = tid + i * 256;   // (m,e) 2048
    float s = 0.f;
#pragma unroll
    for (int cc = 0; cc < 8; ++cc)
      s += part[(((size_t)bh * 8 + cc) * 64) * 32 + idx];
    ctx[(size_t)bh * 2048 + idx] = s;
  }
  if (tid < 64) {
    float s = 0.f;
#pragma unroll
    for (int cc = 0; cc < 8; ++cc) s += partks[((size_t)bh * 8 + cc) * 64 + tid];
    ksum[bh * 64 + tid] = s;
  }
}

// ================= attention out: out = (qp@ctx) / (qp@ksum) =================
__global__ __launch_bounds__(256) void attnout_kernel(
    const float* __restrict__ qp, const float* __restrict__ ctx,
    const float* __restrict__ ksum, float* __restrict__ out, int qtr) {
  __shared__ float ctxS[2048];
  __shared__ float ksS[64];
  __shared__ float qpS[64 * 64];
  int tid = threadIdx.x;
  int rb = blockIdx.x, head = blockIdx.y;
  int tl0 = rb * 64;
  int b = 2 * qtr + (tl0 >> 13);
  int bhg = b * 8 + head;
#pragma unroll
  for (int i = 0; i < 8; ++i) ctxS[tid + i * 256] = ctx[(size_t)bhg * 2048 + tid + i * 256];
  if (tid < 64) ksS[tid] = ksum[bhg * 64 + tid];
#pragma unroll
  for (int i = 0; i < 16; ++i) {
    int idx = tid + i * 256;
    qpS[idx] = qp[(size_t)(tl0 + (idx >> 6)) * 512 + head * 64 + (idx & 63)];
  }
  __syncthreads();
  int e = tid & 31, tg = tid >> 5;
#pragma unroll
  for (int it = 0; it < 8; ++it) {
    int t = it * 8 + tg;
    float num = 0.f, den = 0.f;
#pragma unroll
    for (int m = 0; m < 64; ++m) {
      float qv = qpS[t * 64 + m];
      num += qv * ctxS[m * 32 + e];
      den += qv * ksS[m];
    }
    out[(size_t)(tl0 + t) * 256 + head * 32 + e] = num / den;
  }
}

// ================= mean pool =================
__global__ __launch_bounds__(256) void pool_kernel(
    const float* __restrict__ h, float* __restrict__ pooled) {
  int b = blockIdx.x, chunk = blockIdx.y, j = threadIdx.x;
  const float* hp = h + (size_t)(b * D_S + chunk * 256) * 256 + j;
  float acc = 0.f;
#pragma unroll 4
  for (int s = 0; s < 256; ++s) acc += hp[(size_t)s * 256];
  atomicAdd(pooled + b * 256 + j, acc);
}

__global__ __launch_bounds__(64) void final_kernel(
    const float* __restrict__ pooled, const float* __restrict__ fcw,
    const float* __restrict__ fcb, float* __restrict__ out) {
  int tid = threadIdx.x;
  if (tid >= 16) return;
  int b = tid >> 1, c = tid & 1;
  float acc = 0.f;
  for (int j = 0; j < 256; ++j) acc += pooled[b * 256 + j] * fcw[j * 2 + c];
  out[b * 2 + c] = acc * (1.f / 8192.f) + fcb[c];
}

extern "C" void kernel_launch(void* const* d_in, const int* in_sizes, int n_in,
                              void* d_out, int out_size, void* d_ws, size_t ws_size,
                              hipStream_t stream) {
  const float* x     = (const float*)d_in[0];
  const float* emb_w = (const float*)d_in[1];
  const float* emb_b = (const float*)d_in[2];
  const float* pos   = (const float*)d_in[3];
  const float* ln1_g = (const float*)d_in[4];
  const float* ln1_b = (const float*)d_in[5];
  const float* wq    = (const float*)d_in[6];
  const float* wk    = (const float*)d_in[7];
  const float* wv    = (const float*)d_in[8];
  const float* wo    = (const float*)d_in[9];
  const float* bo    = (const float*)d_in[10];
  const float* ln2_g = (const float*)d_in[11];
  const float* ln2_b = (const float*)d_in[12];
  const float* w1    = (const float*)d_in[13];
  const float* b1    = (const float*)d_in[14];
  const float* w2    = (const float*)d_in[15];
  const float* b2    = (const float*)d_in[16];
  const float* proj  = (const float*)d_in[17];
  const float* fc_w  = (const float*)d_in[18];
  const float* fc_b  = (const float*)d_in[19];

  if (ws_size < NEED_BYTES) {
    report_kernel<<<1, 64, 0, stream>>>((float*)d_out, (float)ws_size);
    return;
  }

  float* ws = (float*)d_ws;
  float* h     = ws + OFF_H;
  float* xn    = ws + OFF_XN;
  float* kp_q  = ws + OFF_B1;                 // 8,388,608
  float* v_q   = ws + OFF_B1 + 8388608;       // 4,194,304
  float* qp_q  = kp_q;
  float* ao_q  = v_q;
  float* mid   = ws + OFF_B1;                 // FFN: full 16.8M
  float* WKP   = ws + OFF_WKP;
  float* WQP   = ws + OFF_WQP;
  float* diagk = ws + OFF_DIAGK;
  float* diagq = ws + OFF_DIAGQ;
  unsigned int* kmaxk = (unsigned int*)(ws + OFF_KMAX);
  float* part  = ws + OFF_PART;
  float* partk = ws + OFF_PARTK;
  float* ctx   = ws + OFF_CTX;
  float* ksum  = ws + OFF_KSUM;
  float* pooled = ws + OFF_POOL;

  embed_kernel<<<TOK, 256, 0, stream>>>(x, emb_w, emb_b, pos, h);

  for (int l = 0; l < D_L; ++l) {
    const float* pj = proj + l * 2048;
    ln_kernel<<<TOK / 4, 256, 0, stream>>>(h, xn, ln1_g + l * 256, ln1_b + l * 256);
    wproj_kernel<<<512, 256, 0, stream>>>(wk + l * 65536, pj, WKP);
    wproj_kernel<<<512, 256, 0, stream>>>(wq + l * 65536, pj, WQP);
    zero_kernel<<<1, 256, 0, stream>>>((float*)kmaxk, 64);
    gemm_max_kernel<<<dim3(1024, 8), 256, 0, stream>>>(xn, WKP, kmaxk);
    gemm_diag_kernel<<<dim3(1024, 4), 256, 0, stream>>>(xn, wk + l * 65536, diagk);
    gemm_diag_kernel<<<dim3(1024, 4), 256, 0, stream>>>(xn, wq + l * 65536, diagq);

    for (int q = 0; q < 4; ++q) {
      const float* xq = xn + (size_t)q * QTOK * 256;
      gemm_kp_kernel<<<dim3(256, 8), 256, 0, stream>>>(xq, WKP, diagk, kmaxk, kp_q, q * QTOK);
      gemm_kernel<0, 0><<<dim3(256, 4), 256, 0, stream>>>(xq, wv + l * 65536, nullptr, v_q, 256, 256);
      ctxaccum_kernel<<<dim3(16, 8), 256, 0, stream>>>(kp_q, v_q, part, partk, q);
    }
    ctxreduce_kernel<<<64, 256, 0, stream>>>(part, partk, ctx, ksum);

    for (int q = 0; q < 4; ++q) {
      const float* xq = xn + (size_t)q * QTOK * 256;
      float* hq = h + (size_t)q * QTOK * 256;
      gemm_qp_kernel<<<dim3(256, 8), 256, 0, stream>>>(xq, WQP, diagq, qp_q, q * QTOK);
      attnout_kernel<<<dim3(256, 8), 256, 0, stream>>>(qp_q, ctx, ksum, ao_q, q);
      gemm_kernel<0, 1><<<dim3(256, 4), 256, 0, stream>>>(ao_q, wo + l * 65536, bo + l * 256, hq, 256, 256);
    }

    ln_kernel<<<TOK / 4, 256, 0, stream>>>(h, xn, ln2_g + l * 256, ln2_b + l * 256);
    for (int q = 0; q < 4; ++q) {
      const float* xq = xn + (size_t)q * QTOK * 256;
      float* hq = h + (size_t)q * QTOK * 256;
      gemm128_kernel<1, 0><<<dim3(128, 8), 256, 0, stream>>>(xq, w1 + l * 262144, b1 + l * 1024, mid, 1024, 256);
      gemm128_kernel<0, 1><<<dim3(128, 2), 256, 0, stream>>>(mid, w2 + l * 262144, b2 + l * 256, hq, 256, 1024);
    }
  }

  zero_kernel<<<8, 256, 0, stream>>>(pooled, 2048);
  pool_kernel<<<dim3(8, 32), 256, 0, stream>>>(h, pooled);
  final_kernel<<<1, 64, 0, stream>>>(pooled, fc_w, fc_b, (float*)d_out);
}

// Round 4
// 6319.018 us; speedup vs baseline: 4.4508x; 2.0319x over previous
//
#include <hip/hip_runtime.h>
#include <math.h>

typedef unsigned short u16;
typedef __attribute__((ext_vector_type(8))) short bf16x8;
typedef __attribute__((ext_vector_type(4))) float f32x4;

// ---- problem dims ----
static constexpr int D_S = 8192;
static constexpr int D_L = 4;
static constexpr int TOK = 65536;
static constexpr float NORMALIZER = 0.4204482076268573f;  // 32^-0.25
static constexpr float RATIO = 0.125f;                    // 64^-0.5
static constexpr float KEPS = 1e-4f;

// ---- workspace layout (float slots) ----
static constexpr size_t OFF_H     = 0;            // 16,777,216 fp32 residual
static constexpr size_t OFF_XNB   = 16777216;     // 8,388,608  bf16 xn [65536][256]
static constexpr size_t OFF_BIG   = 25165824;     // 16,777,216 bf16 xp/kp/qp [65536][512] | FFN mid half
static constexpr size_t OFF_V     = 41943040;     // 4,194,304  bf16 v/ao per-half [32768][256]
static constexpr size_t OFF_WKP   = 46137344;     // 131,072
static constexpr size_t OFF_WQP   = 46268416;     // 131,072
static constexpr size_t OFF_WK    = 46399488;     // 65,536
static constexpr size_t OFF_WQ    = 46465024;     // 65,536
static constexpr size_t OFF_WV    = 46530560;     // 65,536
static constexpr size_t OFF_WO    = 46596096;     // 65,536
static constexpr size_t OFF_W1    = 46661632;     // 262,144
static constexpr size_t OFF_W2    = 46923776;     // 262,144
static constexpr size_t OFF_DGK   = 47185920;     // 262,144 (bf16 65536x8)
static constexpr size_t OFF_DGQ   = 47448064;     // 262,144
static constexpr size_t OFF_KMAX  = 47710208;     // 64
static constexpr size_t OFF_PART  = 47710272;     // 262,144
static constexpr size_t OFF_PARTK = 47972416;     // 8,192
static constexpr size_t OFF_CTX   = 47980608;     // 131,072
static constexpr size_t OFF_KSUM  = 48111680;     // 4,096
static constexpr size_t OFF_POOL  = 48115776;     // 2,048
static constexpr size_t TOTAL_F   = 48117824;
static constexpr size_t NEED_BYTES = TOTAL_F * 4; // 192,471,296 < 201,875,712 proven

static __device__ __forceinline__ float bf2f(u16 u) {
  return __uint_as_float(((unsigned int)u) << 16);
}
static __device__ __forceinline__ u16 f2bf(float f) {
  unsigned int u = __float_as_uint(f);
  u = (u + 0x7fffu + ((u >> 16) & 1u)) >> 16;
  return (u16)u;
}
static __device__ __forceinline__ float geluf(float v) {
  return 0.5f * v * (1.f + erff(v * 0.70710678118654752f));
}

__global__ void report_kernel(float* out, float v) {
  if (threadIdx.x < 16) out[threadIdx.x] = v;
}

__global__ __launch_bounds__(256) void zero_kernel(float* p, int n) {
  int i = blockIdx.x * 256 + threadIdx.x;
  if (i < n) p[i] = 0.f;
}

// ================= embed: h = x @ emb_w + emb_b + pos (fp32) =================
__global__ __launch_bounds__(256) void embed_kernel(
    const float* __restrict__ x, const float* __restrict__ ew,
    const float* __restrict__ eb, const float* __restrict__ pos,
    float* __restrict__ h) {
  __shared__ float xs[64];
  int t = blockIdx.x;
  int j = threadIdx.x;
  if (j < 64) xs[j] = x[t * 64 + j];
  __syncthreads();
  float acc = 0.f;
#pragma unroll 8
  for (int i = 0; i < 64; ++i) acc += xs[i] * ew[i * 256 + j];
  int s = t & (D_S - 1);
  h[(size_t)t * 256 + j] = acc + eb[j] + pos[(size_t)s * 256 + j];
}

// ================= layernorm: fp32 in, bf16 out =================
__global__ __launch_bounds__(256) void ln_kernel(
    const float* __restrict__ src, u16* __restrict__ dst,
    const float* __restrict__ g, const float* __restrict__ b) {
  int wv = threadIdx.x >> 6, lane = threadIdx.x & 63;
  int t = blockIdx.x * 4 + wv;
  const float4 v = *(const float4*)(src + (size_t)t * 256 + lane * 4);
  float s1 = v.x + v.y + v.z + v.w;
  float s2 = v.x * v.x + v.y * v.y + v.z * v.z + v.w * v.w;
  for (int off = 32; off; off >>= 1) {
    s1 += __shfl_xor(s1, off);
    s2 += __shfl_xor(s2, off);
  }
  float mu = s1 * (1.f / 256.f);
  float var = s2 * (1.f / 256.f) - mu * mu;
  float rs = rsqrtf(var + 1e-5f);
  float4 gg = *(const float4*)(g + lane * 4);
  float4 bb = *(const float4*)(b + lane * 4);
  u16 o0 = f2bf((v.x - mu) * rs * gg.x + bb.x);
  u16 o1 = f2bf((v.y - mu) * rs * gg.y + bb.y);
  u16 o2 = f2bf((v.z - mu) * rs * gg.z + bb.z);
  u16 o3 = f2bf((v.w - mu) * rs * gg.w + bb.w);
  uint2 pk;
  pk.x = (unsigned)o0 | ((unsigned)o1 << 16);
  pk.y = (unsigned)o2 | ((unsigned)o3 << 16);
  *(uint2*)(dst + (size_t)t * 256 + lane * 4) = pk;
}

// ===== weight split: fp32 W[K][N] -> bf16 Wt[N][2K] (hi plane, lo plane) =====
__global__ __launch_bounds__(256) void wsplit_kernel(
    const float* __restrict__ W, u16* __restrict__ Wt, int K, int N, int nb) {
  int i = blockIdx.x * 256 + threadIdx.x;
  int k = i >> nb, n = i & (N - 1);
  float val = W[i];
  u16 hi = f2bf(val);
  u16 lo = f2bf(val - bf2f(hi));
  Wt[(size_t)n * 2 * K + k] = hi;
  Wt[(size_t)n * 2 * K + K + k] = lo;
}

// ===== WKP/WQP build+split: Wt[n=h*64+m][2*256], val = norm * sum_d w[k][h*32+d]*proj[m][d] =====
__global__ __launch_bounds__(256) void wprojsplit_kernel(
    const float* __restrict__ w, const float* __restrict__ proj,
    u16* __restrict__ Wt) {
  int i = blockIdx.x * 256 + threadIdx.x;   // 131072
  int k = i & 255, n = i >> 8;
  int head = n >> 6, m = n & 63;
  float s = 0.f;
#pragma unroll
  for (int d = 0; d < 32; ++d) s += w[k * 256 + head * 32 + d] * proj[m * 32 + d];
  s *= NORMALIZER;
  u16 hi = f2bf(s);
  u16 lo = f2bf(s - bf2f(hi));
  Wt[(size_t)n * 512 + k] = hi;
  Wt[(size_t)n * 512 + 256 + k] = lo;
}

// ================= MFMA GEMM: 128x128 tile, A bf16 [M][K], Wt bf16 [N][2K] =================
// EPI: 0 plain (ACT gelu, ACC into fp32, OBF bf16 store), 1 per-head diag, 2 xp-store+max, 3 qp
template <int EPI, int ACT, int ACC, int OBF>
__global__ __launch_bounds__(256) void mfma_gemm(
    const u16* __restrict__ A, const u16* __restrict__ Wt,
    const float* __restrict__ bias, const u16* __restrict__ diagIn,
    float* __restrict__ outF, u16* __restrict__ outB,
    u16* __restrict__ diagOut, unsigned int* __restrict__ kmaxOut,
    int N, int K) {
  __shared__ __align__(16) u16 Als[4096];   // [q][row][8]
  __shared__ __align__(16) u16 Bls[4096];   // [q][col][8]
  const int K2 = K * 2;
  int tid = threadIdx.x;
  int bm = blockIdx.x * 128, bn = blockIdx.y * 128;
  int w = tid >> 6, lane = tid & 63;
  int wm = w >> 1, wn = w & 1;
  int lr = lane & 15, lq = lane >> 4;
  f32x4 acc[4][4];
#pragma unroll
  for (int i = 0; i < 4; ++i)
#pragma unroll
    for (int j = 0; j < 4; ++j) acc[i][j] = (f32x4){0.f, 0.f, 0.f, 0.f};
  int r0 = tid >> 2, q0 = tid & 3;
  for (int k0 = 0; k0 < K2; k0 += 32) {
    __syncthreads();
    int kk = k0 + q0 * 8;
    int gka = kk & (K - 1);
#pragma unroll
    for (int u = 0; u < 2; ++u) {
      int row = r0 + u * 64;
      ((uint4*)Als)[q0 * 128 + row] = *(const uint4*)(A + (size_t)(bm + row) * K + gka);
      ((uint4*)Bls)[q0 * 128 + row] = *(const uint4*)(Wt + (size_t)(bn + row) * K2 + kk);
    }
    __syncthreads();
    bf16x8 af[4], bfr[4];
#pragma unroll
    for (int mi = 0; mi < 4; ++mi)
      af[mi] = ((const bf16x8*)Als)[lq * 128 + wm * 64 + mi * 16 + lr];
#pragma unroll
    for (int ni = 0; ni < 4; ++ni)
      bfr[ni] = ((const bf16x8*)Bls)[lq * 128 + wn * 64 + ni * 16 + lr];
#pragma unroll
    for (int mi = 0; mi < 4; ++mi)
#pragma unroll
      for (int ni = 0; ni < 4; ++ni)
        acc[mi][ni] = __builtin_amdgcn_mfma_f32_16x16x32_bf16(af[mi], bfr[ni], acc[mi][ni], 0, 0, 0);
  }
  // ---- epilogues ----  C/D: col = lane&15, row = (lane>>4)*4 + r  [m89-verified]
  if (EPI == 0) {
#pragma unroll
    for (int ni = 0; ni < 4; ++ni) {
      int col = bn + wn * 64 + ni * 16 + lr;
      float bv = bias ? bias[col] : 0.f;
#pragma unroll
      for (int mi = 0; mi < 4; ++mi)
#pragma unroll
        for (int r = 0; r < 4; ++r) {
          int rowg = bm + wm * 64 + mi * 16 + lq * 4 + r;
          float val = acc[mi][ni][r] + bv;
          if (ACT) val = geluf(val);
          size_t o = (size_t)rowg * N + col;
          if (OBF) outB[o] = f2bf(val);
          else if (ACC) outF[o] += val;
          else outF[o] = val;
        }
    }
  }
  if (EPI == 1) {  // diag per head (32 cols); wave spans 2 heads
    const float c05n2 = 0.5f * NORMALIZER * NORMALIZER;
    int hb = (bn + wn * 64) >> 5;
#pragma unroll
    for (int mi = 0; mi < 4; ++mi) {
      float s0[4] = {0.f, 0.f, 0.f, 0.f}, s1[4] = {0.f, 0.f, 0.f, 0.f};
#pragma unroll
      for (int ni = 0; ni < 4; ++ni)
#pragma unroll
        for (int r = 0; r < 4; ++r) {
          float v = acc[mi][ni][r];
          if (ni < 2) s0[r] += v * v; else s1[r] += v * v;
        }
#pragma unroll
      for (int r = 0; r < 4; ++r) {
        float a = s0[r], b = s1[r];
        a += __shfl_xor(a, 1); a += __shfl_xor(a, 2); a += __shfl_xor(a, 4); a += __shfl_xor(a, 8);
        b += __shfl_xor(b, 1); b += __shfl_xor(b, 2); b += __shfl_xor(b, 4); b += __shfl_xor(b, 8);
        if (lr == 0) {
          int rowg = bm + wm * 64 + mi * 16 + lq * 4 + r;
          diagOut[(size_t)rowg * 8 + hb] = f2bf(c05n2 * a);
          diagOut[(size_t)rowg * 8 + hb + 1] = f2bf(c05n2 * b);
        }
      }
    }
  }
  if (EPI == 2) {  // store bf16 xp + global max per (b, head)
    float mx = -3.4e38f;
#pragma unroll
    for (int mi = 0; mi < 4; ++mi)
#pragma unroll
      for (int ni = 0; ni < 4; ++ni)
#pragma unroll
        for (int r = 0; r < 4; ++r) {
          float v = acc[mi][ni][r];
          mx = fmaxf(mx, v);
          int rowg = bm + wm * 64 + mi * 16 + lq * 4 + r;
          int col = bn + wn * 64 + ni * 16 + lr;
          outB[(size_t)rowg * N + col] = f2bf(v);
        }
#pragma unroll
    for (int off = 1; off < 64; off <<= 1) mx = fmaxf(mx, __shfl_xor(mx, off));
    if (lane == 0) {
      int b = bm >> 13;
      int head = (bn + wn * 64) >> 6;
      unsigned int u = __float_as_uint(mx);
      unsigned int key = (u & 0x80000000u) ? ~u : (u | 0x80000000u);
      atomicMax(kmaxOut + b * 8 + head, key);
    }
  }
  if (EPI == 3) {  // qp: in-wave row-max over the head's 64 cols, then exp
    int head = (bn + wn * 64) >> 6;
#pragma unroll
    for (int mi = 0; mi < 4; ++mi) {
      float rm[4] = {-3.4e38f, -3.4e38f, -3.4e38f, -3.4e38f};
#pragma unroll
      for (int ni = 0; ni < 4; ++ni)
#pragma unroll
        for (int r = 0; r < 4; ++r) rm[r] = fmaxf(rm[r], acc[mi][ni][r]);
#pragma unroll
      for (int r = 0; r < 4; ++r) {
        float t = rm[r];
        t = fmaxf(t, __shfl_xor(t, 1)); t = fmaxf(t, __shfl_xor(t, 2));
        t = fmaxf(t, __shfl_xor(t, 4)); t = fmaxf(t, __shfl_xor(t, 8));
        rm[r] = t;
      }
#pragma unroll
      for (int r = 0; r < 4; ++r) {
        int rowg = bm + wm * 64 + mi * 16 + lq * 4 + r;
        float dg = bf2f(diagIn[(size_t)rowg * 8 + head]);
#pragma unroll
        for (int ni = 0; ni < 4; ++ni) {
          int col = bn + wn * 64 + ni * 16 + lr;
          float v = RATIO * (__expf(acc[mi][ni][r] - dg - rm[r]) + KEPS);
          outB[(size_t)rowg * N + col] = f2bf(v);
        }
      }
    }
  }
}

// ================= kexp: in-place kp = ratio*(exp(xp - diag - mx) + eps) =================
__global__ __launch_bounds__(256) void kexp_kernel(
    u16* __restrict__ xp, const u16* __restrict__ diagk,
    const unsigned int* __restrict__ kmaxk) {
  size_t i = ((size_t)blockIdx.x * 256 + threadIdx.x) * 8;
  int t = (int)(i >> 9), m0 = (int)(i & 511);
  int head = m0 >> 6, b = t >> 13;
  float dg = bf2f(diagk[(size_t)t * 8 + head]);
  unsigned int mk = kmaxk[b * 8 + head];
  float mx = __uint_as_float((mk & 0x80000000u) ? (mk & 0x7fffffffu) : ~mk);
  u16 vv[8];
  *(uint4*)vv = *(const uint4*)(xp + i);
#pragma unroll
  for (int j = 0; j < 8; ++j)
    vv[j] = f2bf(RATIO * (__expf(bf2f(vv[j]) - dg - mx) + KEPS));
  *(uint4*)(xp + i) = *(uint4*)vv;
}

// ===== ctxaccum: partials per (bh, in-batch chunk of 4096): part[m][e] = sum kp*v =====
__global__ __launch_bounds__(256) void ctxaccum_kernel(
    const u16* __restrict__ kp, const u16* __restrict__ v,
    float* __restrict__ part, float* __restrict__ partk, int hf) {
  __shared__ float kpS[64 * 64];
  __shared__ float vS[64 * 32];
  int tid = threadIdx.x;
  int bl = blockIdx.x >> 3, head = blockIdx.x & 7, c = blockIdx.y;
  int n0l = bl * 8192 + c * 4096;
  int bhg = (hf * 4 + bl) * 8 + head;
  int m = tid & 63, eg = tid >> 6;
  float acc[8] = {};
  float ks = 0.f;
  const u16* kpb = kp + (size_t)(hf * 32768 + n0l) * 512 + head * 64;
  const u16* vb = v + (size_t)n0l * 256 + head * 32;
  for (int tile = 0; tile < 64; ++tile) {
    int nb = tile * 64;
    __syncthreads();
#pragma unroll
    for (int i = 0; i < 16; ++i) {
      int idx = tid + i * 256;
      kpS[idx] = bf2f(kpb[(size_t)(nb + (idx >> 6)) * 512 + (idx & 63)]);
    }
#pragma unroll
    for (int i = 0; i < 8; ++i) {
      int idx = tid + i * 256;
      vS[idx] = bf2f(vb[(size_t)(nb + (idx >> 5)) * 256 + (idx & 31)]);
    }
    __syncthreads();
#pragma unroll 4
    for (int n = 0; n < 64; ++n) {
      float kv = kpS[n * 64 + m];
      if (eg == 0) ks += kv;
      const float* vr = &vS[n * 32 + eg * 8];
#pragma unroll
      for (int j = 0; j < 8; ++j) acc[j] += kv * vr[j];
    }
  }
  float* pp = part + ((size_t)bhg * 2 + c) * 2048 + m * 32 + eg * 8;
#pragma unroll
  for (int j = 0; j < 8; ++j) pp[j] = acc[j];
  if (eg == 0) partk[((size_t)bhg * 2 + c) * 64 + m] = ks;
}

__global__ __launch_bounds__(256) void ctxreduce_kernel(
    const float* __restrict__ part, const float* __restrict__ partk,
    float* __restrict__ ctx, float* __restrict__ ksum) {
  int bh = blockIdx.x, tid = threadIdx.x;
#pragma unroll
  for (int i = 0; i < 8; ++i) {
    int idx = tid + i * 256;
    ctx[(size_t)bh * 2048 + idx] =
        part[((size_t)bh * 2 + 0) * 2048 + idx] + part[((size_t)bh * 2 + 1) * 2048 + idx];
  }
  if (tid < 64)
    ksum[bh * 64 + tid] = partk[(size_t)bh * 2 * 64 + tid] + partk[((size_t)bh * 2 + 1) * 64 + tid];
}

// ================= attnout: ao = (qp@ctx)/(qp@ksum), bf16 out =================
__global__ __launch_bounds__(256) void attnout_kernel(
    const u16* __restrict__ qp, const float* __restrict__ ctx,
    const float* __restrict__ ksum, u16* __restrict__ ao, int hf) {
  __shared__ float ctxS[2048];
  __shared__ float ksS[64];
  __shared__ float qpS[64 * 64];
  int tid = threadIdx.x;
  int rb = blockIdx.x, head = blockIdx.y;
  int n0l = rb * 64;
  int t0g = hf * 32768 + n0l;
  int bhg = (t0g >> 13) * 8 + head;
#pragma unroll
  for (int i = 0; i < 8; ++i) ctxS[tid + i * 256] = ctx[(size_t)bhg * 2048 + tid + i * 256];
  if (tid < 64) ksS[tid] = ksum[bhg * 64 + tid];
#pragma unroll
  for (int i = 0; i < 16; ++i) {
    int idx = tid + i * 256;
    qpS[idx] = bf2f(qp[(size_t)(t0g + (idx >> 6)) * 512 + head * 64 + (idx & 63)]);
  }
  __syncthreads();
  int e = tid & 31, tg = tid >> 5;
#pragma unroll
  for (int it = 0; it < 8; ++it) {
    int t = it * 8 + tg;
    float num = 0.f, den = 0.f;
#pragma unroll
    for (int m = 0; m < 64; ++m) {
      float qv = qpS[t * 64 + m];
      num += qv * ctxS[m * 32 + e];
      den += qv * ksS[m];
    }
    ao[(size_t)(n0l + t) * 256 + head * 32 + e] = f2bf(num / den);
  }
}

// ================= mean pool + final FC (fp32 h) =================
__global__ __launch_bounds__(256) void pool_kernel(
    const float* __restrict__ h, float* __restrict__ pooled) {
  int b = blockIdx.x, chunk = blockIdx.y, j = threadIdx.x;
  const float* hp = h + (size_t)(b * D_S + chunk * 256) * 256 + j;
  float acc = 0.f;
#pragma unroll 4
  for (int s = 0; s < 256; ++s) acc += hp[(size_t)s * 256];
  atomicAdd(pooled + b * 256 + j, acc);
}

__global__ __launch_bounds__(64) void final_kernel(
    const float* __restrict__ pooled, const float* __restrict__ fcw,
    const float* __restrict__ fcb, float* __restrict__ out) {
  int tid = threadIdx.x;
  if (tid >= 16) return;
  int b = tid >> 1, c = tid & 1;
  float acc = 0.f;
  for (int j = 0; j < 256; ++j) acc += pooled[b * 256 + j] * fcw[j * 2 + c];
  out[b * 2 + c] = acc * (1.f / 8192.f) + fcb[c];
}

extern "C" void kernel_launch(void* const* d_in, const int* in_sizes, int n_in,
                              void* d_out, int out_size, void* d_ws, size_t ws_size,
                              hipStream_t stream) {
  const float* x     = (const float*)d_in[0];
  const float* emb_w = (const float*)d_in[1];
  const float* emb_b = (const float*)d_in[2];
  const float* pos   = (const float*)d_in[3];
  const float* ln1_g = (const float*)d_in[4];
  const float* ln1_b = (const float*)d_in[5];
  const float* wq    = (const float*)d_in[6];
  const float* wk    = (const float*)d_in[7];
  const float* wv    = (const float*)d_in[8];
  const float* wo    = (const float*)d_in[9];
  const float* bo    = (const float*)d_in[10];
  const float* ln2_g = (const float*)d_in[11];
  const float* ln2_b = (const float*)d_in[12];
  const float* w1    = (const float*)d_in[13];
  const float* b1    = (const float*)d_in[14];
  const float* w2    = (const float*)d_in[15];
  const float* b2    = (const float*)d_in[16];
  const float* proj  = (const float*)d_in[17];
  const float* fc_w  = (const float*)d_in[18];
  const float* fc_b  = (const float*)d_in[19];

  if (ws_size < NEED_BYTES) {
    report_kernel<<<1, 64, 0, stream>>>((float*)d_out, (float)ws_size);
    return;
  }

  float* ws = (float*)d_ws;
  float* h      = ws + OFF_H;
  u16* xnb      = (u16*)(ws + OFF_XNB);
  u16* BIG      = (u16*)(ws + OFF_BIG);
  u16* Vb       = (u16*)(ws + OFF_V);
  u16* WKPt     = (u16*)(ws + OFF_WKP);
  u16* WQPt     = (u16*)(ws + OFF_WQP);
  u16* WKt      = (u16*)(ws + OFF_WK);
  u16* WQt      = (u16*)(ws + OFF_WQ);
  u16* WVt      = (u16*)(ws + OFF_WV);
  u16* WOt      = (u16*)(ws + OFF_WO);
  u16* W1t      = (u16*)(ws + OFF_W1);
  u16* W2t      = (u16*)(ws + OFF_W2);
  u16* dgk      = (u16*)(ws + OFF_DGK);
  u16* dgq      = (u16*)(ws + OFF_DGQ);
  unsigned int* kmaxk = (unsigned int*)(ws + OFF_KMAX);
  float* part   = ws + OFF_PART;
  float* partk  = ws + OFF_PARTK;
  float* ctx    = ws + OFF_CTX;
  float* ksum   = ws + OFF_KSUM;
  float* pooled = ws + OFF_POOL;

  embed_kernel<<<TOK, 256, 0, stream>>>(x, emb_w, emb_b, pos, h);

  for (int l = 0; l < D_L; ++l) {
    const float* pj = proj + l * 2048;
    ln_kernel<<<TOK / 4, 256, 0, stream>>>(h, xnb, ln1_g + l * 256, ln1_b + l * 256);
    wprojsplit_kernel<<<512, 256, 0, stream>>>(wk + l * 65536, pj, WKPt);
    wprojsplit_kernel<<<512, 256, 0, stream>>>(wq + l * 65536, pj, WQPt);
    wsplit_kernel<<<256, 256, 0, stream>>>(wk + l * 65536, WKt, 256, 256, 8);
    wsplit_kernel<<<256, 256, 0, stream>>>(wq + l * 65536, WQt, 256, 256, 8);
    wsplit_kernel<<<256, 256, 0, stream>>>(wv + l * 65536, WVt, 256, 256, 8);
    wsplit_kernel<<<256, 256, 0, stream>>>(wo + l * 65536, WOt, 256, 256, 8);
    wsplit_kernel<<<1024, 256, 0, stream>>>(w1 + l * 262144, W1t, 256, 1024, 10);
    wsplit_kernel<<<1024, 256, 0, stream>>>(w2 + l * 262144, W2t, 1024, 256, 8);
    zero_kernel<<<1, 256, 0, stream>>>((float*)kmaxk, 64);

    // diag(k), diag(q)
    mfma_gemm<1, 0, 0, 0><<<dim3(512, 2), 256, 0, stream>>>(
        xnb, WKt, nullptr, nullptr, nullptr, nullptr, dgk, nullptr, 256, 256);
    mfma_gemm<1, 0, 0, 0><<<dim3(512, 2), 256, 0, stream>>>(
        xnb, WQt, nullptr, nullptr, nullptr, nullptr, dgq, nullptr, 256, 256);
    // xp + global max
    mfma_gemm<2, 0, 0, 1><<<dim3(512, 4), 256, 0, stream>>>(
        xnb, WKPt, nullptr, nullptr, nullptr, BIG, nullptr, kmaxk, 512, 256);
    // kp = exp(xp - diag - mx), in place
    kexp_kernel<<<16384, 256, 0, stream>>>(BIG, dgk, kmaxk);
    // context accumulation per half
    for (int hf = 0; hf < 2; ++hf) {
      const u16* xh = xnb + (size_t)hf * 32768 * 256;
      mfma_gemm<0, 0, 0, 1><<<dim3(256, 2), 256, 0, stream>>>(
          xh, WVt, nullptr, nullptr, nullptr, Vb, nullptr, nullptr, 256, 256);
      ctxaccum_kernel<<<dim3(32, 2), 256, 0, stream>>>(BIG, Vb, part, partk, hf);
    }
    ctxreduce_kernel<<<64, 256, 0, stream>>>(part, partk, ctx, ksum);
    // qp (overwrites BIG; kp dead)
    mfma_gemm<3, 0, 0, 1><<<dim3(512, 4), 256, 0, stream>>>(
        xnb, WQPt, nullptr, dgq, nullptr, BIG, nullptr, nullptr, 512, 256);
    for (int hf = 0; hf < 2; ++hf) {
      float* hh = h + (size_t)hf * 32768 * 256;
      attnout_kernel<<<dim3(512, 8), 256, 0, stream>>>(BIG, ctx, ksum, Vb, hf);
      mfma_gemm<0, 0, 1, 0><<<dim3(256, 2), 256, 0, stream>>>(
          Vb, WOt, bo + l * 256, nullptr, hh, nullptr, nullptr, nullptr, 256, 256);
    }

    ln_kernel<<<TOK / 4, 256, 0, stream>>>(h, xnb, ln2_g + l * 256, ln2_b + l * 256);
    for (int hf = 0; hf < 2; ++hf) {
      const u16* xh = xnb + (size_t)hf * 32768 * 256;
      float* hh = h + (size_t)hf * 32768 * 256;
      mfma_gemm<0, 1, 0, 1><<<dim3(256, 8), 256, 0, stream>>>(
          xh, W1t, b1 + l * 1024, nullptr, nullptr, BIG, nullptr, nullptr, 1024, 256);
      mfma_gemm<0, 0, 1, 0><<<dim3(256, 2), 256, 0, stream>>>(
          BIG, W2t, b2 + l * 256, nullptr, hh, nullptr, nullptr, nullptr, 256, 1024);
    }
  }

  zero_kernel<<<8, 256, 0, stream>>>(pooled, 2048);
  pool_kernel<<<dim3(8, 32), 256, 0, stream>>>(h, pooled);
  final_kernel<<<1, 64, 0, stream>>>(pooled, fc_w, fc_b, (float*)d_out);
}